// Round 19
// baseline (139.133 us; speedup 1.0000x reference)
//
#include <hip/hip_runtime.h>
#include <stdint.h>

#define BB 16
#define CC 2048
#define DD 256
#define MM (BB*CC)

typedef __attribute__((ext_vector_type(4))) float f32x4;
typedef __attribute__((ext_vector_type(8))) short bf16x8;
typedef __attribute__((ext_vector_type(4))) short s16x4;

static __device__ __forceinline__ short f2bf(float f) {
  union { float f; uint32_t u; } v; v.f = f;
  uint32_t u = v.u;
  return (short)((u + 0x7FFFu + ((u >> 16) & 1u)) >> 16);
}

// async global->LDS, 16B per lane, dest = uniform base + lane*16
#define GLDS16(gp, lp) __builtin_amdgcn_global_load_lds(                      \
    (const __attribute__((address_space(1))) void*)(gp),                      \
    (__attribute__((address_space(3))) void*)(lp), 16, 0, 0)

// DPP row_ror reduction step over the 16-lane group (ror n)
#define DPP_ROR_F(x, n) __uint_as_float(__builtin_amdgcn_update_dpp(          \
    0, (int)__float_as_uint(x), 0x120 + (n), 0xF, 0xF, false))

// ---------------------------------------------------------------------------
// Kernel 1 (fused prep): blocks 0..63 build the cos/sin table; blocks 64..255
// convert W{q,k,v} f32->bf16 into 24KB half-e steps: step s (kc=s>>1, eh=s&1)
// = [mat 8KB][e_local row 64B, in-row slot XOR (((e>>1)&3)<<4)].
// ---------------------------------------------------------------------------
__global__ __launch_bounds__(256) void k_prep(
    const float* __restrict__ Wq, const float* __restrict__ Wk,
    const float* __restrict__ Wv, short* __restrict__ wb,
    float2* __restrict__ cs) {
  const int bid = blockIdx.x;
  if (bid < 64) {
    int id = bid * 256 + threadIdx.x;            // 16384 threads
    int k = id & 127, pg = id >> 7;
    double th = pow(10000.0, (1.0 - (double)k) * (1.0 / 128.0));
    const double TWO_PI = 6.283185307179586476925287;
    const double INV_2PI = 1.0 / TWO_PI;
    #pragma unroll
    for (int i = 0; i < 16; ++i) {
      int pos = pg * 16 + i;
      double ang = (double)pos * th;
      double red = ang - floor(ang * INV_2PI) * TWO_PI;
      float fr = (float)red;
      cs[(size_t)pos * 128 + k] = make_float2(__cosf(fr), __sinf(fr));
    }
  } else {
    int gid = (bid - 64) * 256 + threadIdx.x;    // 49152 groups of 8B
    int s = gid / 3072;                          // 3072 groups per 24KB step
    int og = gid - s * 3072;
    int mat = og >> 10;                          // 1024 groups per mat slice
    int o = (og & 1023) * 8;                     // byte offset in mat slice
    int e_local = o >> 6;
    int e = (s & 1) * 128 + e_local;
    int kc = s >> 1;
    int c4 = ((o & 63) ^ (((e >> 1) & 3) << 4)) >> 3;
    const float* W = (mat == 0) ? Wq : (mat == 1) ? Wk : Wv;
    f32x4 wv = *(const f32x4*)(W + (size_t)e * DD + kc * 32 + c4 * 4);
    s16x4 b4;
    b4[0] = f2bf(wv[0]); b4[1] = f2bf(wv[1]); b4[2] = f2bf(wv[2]); b4[3] = f2bf(wv[3]);
    *(s16x4*)((char*)wb + (size_t)gid * 8) = b4;
  }
}

// ---------------------------------------------------------------------------
// Kernel 2: fused QKV projection + RoPE, COLUMN-partitioned waves.
// 256 thr, 64 rows/block, 80KB LDS -> 2 blocks/CU (proven occupancy).
// Wave w owns col-tiles {w, w+4, w+8, w+12} of EACH matrix: per slot it
// reads 4 A-frags (all rows) + 6 B-frags (own cols) = 10 b128 vs 25 --
// 2.5x less LDS-read traffic at identical MFMA count (24/slot).
// Slot = proven single-barrier dbuf: vmcnt(0); barrier; STAGE(next); compute.
// acc[3][4][4] = 192 VGPR, all indices compile-time.
// ---------------------------------------------------------------------------
__global__ __launch_bounds__(256, 2) void k_qkv(
    const float* __restrict__ x, const short* __restrict__ wb,
    const float* __restrict__ bq, const float* __restrict__ bk,
    const float* __restrict__ bv, const float2* __restrict__ cs,
    short* __restrict__ q_rot, short* __restrict__ k_rot,
    short* __restrict__ v_t)
{
  __shared__ char SM[81920];           // xs 32KB | wsh dbuf 2x24KB
  short* xs = (short*)SM;              // [64 rows][512B], swz (row&7)<<4
  char* wsh = SM + 32768;
  const int t = threadIdx.x;
  const int lane = t & 63, w = t >> 6; // 4 waves
  const int g = lane >> 4, li = lane & 15;
  const int m0 = blockIdx.x * 64;

  // stage x tile (f32 -> bf16), swizzled rows 512B
  #pragma unroll
  for (int i = 0; i < 16; ++i) {
    int chunk = i * 256 + t;           // 4096 chunks of 4 f32
    int row = chunk >> 6, c4 = chunk & 63;
    f32x4 xv = *(const f32x4*)(x + (size_t)(m0 + row) * DD + c4 * 4);
    s16x4 b4;
    b4[0] = f2bf(xv[0]); b4[1] = f2bf(xv[1]); b4[2] = f2bf(xv[2]); b4[3] = f2bf(xv[3]);
    *(s16x4*)((char*)xs + row * 512 + ((c4 * 8) ^ ((row & 7) << 4))) = b4;
  }

  auto STAGE = [&](int buf, int s) {   // 24 x 1KB chunks over 4 waves
    #pragma unroll
    for (int i = 0; i < 6; ++i) {
      int cc = i * 4 + w;
      const char* src = (const char*)wb + s * 24576 + cc * 1024 + lane * 16;
      GLDS16(src, wsh + buf * 24576 + cc * 1024);
    }
  };

  STAGE(0, 0);
  __syncthreads();                     // xs ready; STAGE(0) issued

  f32x4 zero4 = {0.f, 0.f, 0.f, 0.f};
  f32x4 acc[3][4][4];                  // [mat][col-slot s][row-tile rt]
  #pragma unroll
  for (int m = 0; m < 3; ++m)
    #pragma unroll
    for (int s = 0; s < 4; ++s)
      #pragma unroll
      for (int rt = 0; rt < 4; ++rt) acc[m][s][rt] = zero4;

  #pragma unroll
  for (int kc = 0; kc < 8; ++kc) {
    #pragma unroll
    for (int eh = 0; eh < 2; ++eh) {
      const int st = kc * 2 + eh;
      asm volatile("s_waitcnt vmcnt(0)" ::: "memory");  // my STAGE(st) landed
      __builtin_amdgcn_sched_barrier(0);
      __builtin_amdgcn_s_barrier();    // all stages landed + all done st-1
      if (st + 1 < 16) STAGE((st + 1) & 1, st + 1);     // WAR-safe after bar

      const char* Wb = wsh + (st & 1) * 24576;

      bf16x8 a[4];                     // all 4 row-tiles (shared across cols)
      #pragma unroll
      for (int rt = 0; rt < 4; ++rt) {
        int arow = rt * 16 + li;
        a[rt] = *(const bf16x8*)((char*)xs + arow * 512 +
                                 (((kc * 64) + g * 16) ^ ((arow & 7) << 4)));
      }
      #pragma unroll
      for (int m = 0; m < 3; ++m) {
        #pragma unroll
        for (int ss = 0; ss < 2; ++ss) {
          int ctl = w + 4 * ss;        // local col-tile in this eh-half
          int e_local = ctl * 16 + li;
          int off = m * 8192 + e_local * 64 +
                    ((g * 16) ^ (((li >> 1) & 3) << 4));
          bf16x8 bf = *(const bf16x8*)(Wb + off);
          acc[m][eh * 2 + ss][0] = __builtin_amdgcn_mfma_f32_16x16x32_bf16(a[0], bf, acc[m][eh * 2 + ss][0], 0, 0, 0);
          acc[m][eh * 2 + ss][1] = __builtin_amdgcn_mfma_f32_16x16x32_bf16(a[1], bf, acc[m][eh * 2 + ss][1], 0, 0, 0);
          acc[m][eh * 2 + ss][2] = __builtin_amdgcn_mfma_f32_16x16x32_bf16(a[2], bf, acc[m][eh * 2 + ss][2], 0, 0, 0);
          acc[m][eh * 2 + ss][3] = __builtin_amdgcn_mfma_f32_16x16x32_bf16(a[3], bf, acc[m][eh * 2 + ss][3], 0, 0, 0);
        }
      }
    }
  }

  // q,k epilogue: bias + RoPE, direct stores (g-group 32B segments)
  #pragma unroll
  for (int m = 0; m < 2; ++m) {
    short* dst = m ? k_rot : q_rot;
    const float* bp = m ? bk : bq;
    const float qs = m ? 1.0f : 0.0625f;       // 1/sqrt(D) folded into q
    #pragma unroll
    for (int s = 0; s < 4; ++s) {
      int e = (w + 4 * s) * 16 + li;
      float bias = bp[e];
      #pragma unroll
      for (int rt = 0; rt < 4; ++rt) {
        #pragma unroll
        for (int r = 0; r < 4; ++r) {
          int mr = m0 + rt * 16 + g * 4 + r;
          float2 csv = cs[(size_t)(mr & (CC - 1)) * 128 + (e >> 1)];
          float val = acc[m][s][rt][r] + bias;
          float other = __shfl_xor(val, 1);    // pair partner (e^1)
          val = csv.x * val + ((e & 1) ? csv.y * other : -csv.y * other);
          dst[(size_t)mr * DD + e] = f2bf(val * qs);
        }
      }
    }
  }
  // v epilogue: transposed, r-contiguous -> 8B stores
  {
    const int bb = m0 >> 11, c0 = m0 & (CC - 1);
    #pragma unroll
    for (int s = 0; s < 4; ++s) {
      int e = (w + 4 * s) * 16 + li;
      float bias = bv[e];
      #pragma unroll
      for (int rt = 0; rt < 4; ++rt) {
        s16x4 o4;
        #pragma unroll
        for (int r = 0; r < 4; ++r) o4[r] = f2bf(acc[2][s][rt][r] + bias);
        *(s16x4*)(v_t + ((size_t)(bb * DD + e)) * CC + c0 + rt * 16 + g * 4) = o4;
      }
    }
  }
}

// ---------------------------------------------------------------------------
// Kernel 3: causal flash attention (proven 118us round-14 version,
// byte-identical). 256 blocks x 512 thr = 1 block/CU, 8 waves (2/SIMD).
// Pair {j, 31-j} -> exactly 33 group-iters. 2 kv-groups of 4 waves,
// per-group dbuf K+V. Single barrier/slot. DPP softmax; LDS merge.
// ---------------------------------------------------------------------------
__global__ __launch_bounds__(512, 2) void k_attn(
    const short* __restrict__ q_rot, const short* __restrict__ k_rot,
    const short* __restrict__ v_t, float* __restrict__ out)
{
  // LDS: KV [0,128K): group g buf b at (g*2+b)*32768 {K 16KB | V 16KB}
  //      U  [64K, 64K+66560)  (merge, reuses group-1 KV space + a bit)
  //      P  [132608, +8*1280) ; ML [142848, +512)
  __shared__ char SM[143360];
  const int t = threadIdx.x;
  const int lane = t & 63, w = t >> 6;          // 8 waves
  const int wg = w & 3, gq = w >> 2;            // wave-in-group, kv-group
  const int g = lane >> 4, li = lane & 15;

  const int p = blockIdx.x;                     // 256 blocks, 1/CU
  const int b = p & 15;                         // batch -> XCD p%8 fixed
  const int j = p >> 4;                         // 0..15 pair index

  const short* kbase = k_rot + (size_t)b * CC * DD;
  const short* vbase = v_t  + (size_t)b * DD * CC;

  float* U  = (float*)(SM + 65536);             // [64][260] f32
  float* ML = (float*)(SM + 142848);            // [64][2]
  char* Pb = SM + 132608 + w * 1280;            // [16 q][40 sh] pitch 80B

  f32x4 zero4 = {0.f, 0.f, 0.f, 0.f};

  for (int tt = 0; tt < 2; ++tt) {
    const int qt = tt ? (31 - j) : j;           // pair sums to 33 group-iters
    const int q0 = qt * 64;
    const int NTg = qt + 1;                     // kv tiles of 32 per group
    const int kvoff = gq * 32 * NTg;            // group kv start

    // Q fragments: rows q0 + wg*16 + li
    const short* qb = q_rot + ((size_t)b * CC + q0 + wg * 16 + li) * DD;
    bf16x8 qf[8];
    #pragma unroll
    for (int dc = 0; dc < 8; ++dc)
      qf[dc] = *(const bf16x8*)(qb + dc * 32 + g * 8);

    f32x4 O[16];
    #pragma unroll
    for (int i = 0; i < 16; ++i) O[i] = zero4;
    float mrow[4], lrow[4];
    #pragma unroll
    for (int r = 0; r < 4; ++r) { mrow[r] = -__builtin_inff(); lrow[r] = 0.f; }

    auto STAGE = [&](int buf, int kt) {         // 8 GLDS16 per wave
      const int k0s = kvoff + kt * 32;
      char* dst = SM + (size_t)(gq * 2 + buf) * 32768;
      #pragma unroll
      for (int i = 0; i < 4; ++i) {             // K tile: 16 x 1KB chunks
        int c = i * 4 + wg;
        int row = 2 * c + (lane >> 5);
        int cb = ((lane & 31) * 16) ^ ((row & 7) << 4);
        const char* src = (const char*)(kbase + (size_t)(k0s + row) * DD) + cb;
        GLDS16(src, dst + c * 1024);
      }
      #pragma unroll
      for (int i = 0; i < 4; ++i) {             // V tile: 16 x 1KB chunks
        int c = i * 4 + wg;
        int d = 16 * c + (lane >> 2);
        int sb = (((lane & 3) ^ ((lane >> 3) & 3)) * 16);
        const char* src = (const char*)(vbase + (size_t)d * CC + k0s) + sb;
        GLDS16(src, dst + 16384 + c * 1024);
      }
    };

    int cur = 0;
    STAGE(0, 0);
    for (int kt = 0; kt < NTg; ++kt) {
      const int k0 = kvoff + kt * 32;
      asm volatile("s_waitcnt vmcnt(0)" ::: "memory");   // my stage landed
      __builtin_amdgcn_sched_barrier(0);
      __builtin_amdgcn_s_barrier();             // all stages landed AND all
                                                // waves done reading kt-1
      if (kt + 1 < NTg) STAGE(cur ^ 1, kt + 1); // WAR-safe after barrier

      const char* Kb = SM + (size_t)(gq * 2 + cur) * 32768;
      const char* Vb = Kb + 16384;

      // S = Q K^T (scale folded into q)
      f32x4 S[2];
      S[0] = zero4; S[1] = zero4;
      __builtin_amdgcn_s_setprio(1);
      #pragma unroll
      for (int dc = 0; dc < 8; ++dc) {
        #pragma unroll
        for (int nt = 0; nt < 2; ++nt) {
          int krow = nt * 16 + li;
          bf16x8 kf = *(const bf16x8*)(Kb + krow * 512 +
                                       (((dc * 64) + g * 16) ^ ((krow & 7) << 4)));
          S[nt] = __builtin_amdgcn_mfma_f32_16x16x32_bf16(qf[dc], kf, S[nt], 0, 0, 0);
        }
      }
      __builtin_amdgcn_s_setprio(0);

      // causal mask (finite sentinel); uniform cheap test
      if (k0 + 31 > q0) {
        #pragma unroll
        for (int nt = 0; nt < 2; ++nt)
          #pragma unroll
          for (int r = 0; r < 4; ++r)
            if ((k0 + nt * 16 + li) > (q0 + wg * 16 + g * 4 + r))
              S[nt][r] = -1.0e30f;
      }

      // online softmax, DPP row_ror reductions, defer-max (THR=8)
      float mxr[4];
      #pragma unroll
      for (int r = 0; r < 4; ++r) {
        float mx = fmaxf(S[0][r], S[1][r]);
        mx = fmaxf(mx, DPP_ROR_F(mx, 8));
        mx = fmaxf(mx, DPP_ROR_F(mx, 4));
        mx = fmaxf(mx, DPP_ROR_F(mx, 2));
        mx = fmaxf(mx, DPP_ROR_F(mx, 1));
        mxr[r] = mx;
      }
      int need = 0;
      #pragma unroll
      for (int r = 0; r < 4; ++r) need |= (mxr[r] > mrow[r] + 8.f) ? 1 : 0;
      if (__any(need)) {
        #pragma unroll
        for (int r = 0; r < 4; ++r) {
          float mnew = fmaxf(mrow[r], mxr[r]);
          float al = __expf(mrow[r] - mnew);
          mrow[r] = mnew;
          lrow[r] *= al;
          #pragma unroll
          for (int dt2 = 0; dt2 < 16; ++dt2) O[dt2][r] *= al;
        }
      }
      #pragma unroll
      for (int r = 0; r < 4; ++r) {
        float rsum = 0.f;
        #pragma unroll
        for (int nt = 0; nt < 2; ++nt) {
          float pv = __expf(S[nt][r] - mrow[r]);
          S[nt][r] = pv;
          rsum += pv;
        }
        rsum += DPP_ROR_F(rsum, 8);
        rsum += DPP_ROR_F(rsum, 4);
        rsum += DPP_ROR_F(rsum, 2);
        rsum += DPP_ROR_F(rsum, 1);
        lrow[r] += rsum;
      }

      // P (C-layout) -> per-wave LDS (pitch 80) -> A-frag
      #pragma unroll
      for (int nt = 0; nt < 2; ++nt)
        #pragma unroll
        for (int r = 0; r < 4; ++r)
          *(short*)(Pb + (g * 4 + r) * 80 + (nt * 16 + li) * 2) = f2bf(S[nt][r]);

      bf16x8 pf = *(const bf16x8*)(Pb + li * 80 + g * 16);

      // O += P V
      __builtin_amdgcn_s_setprio(1);
      #pragma unroll
      for (int dt2 = 0; dt2 < 16; ++dt2) {
        bf16x8 vf = *(const bf16x8*)(Vb + (dt2 * 16 + li) * 64 +
                                     ((g * 16) ^ (((li >> 1) & 3) << 4)));
        O[dt2] = __builtin_amdgcn_mfma_f32_16x16x32_bf16(pf, vf, O[dt2], 0, 0, 0);
      }
      __builtin_amdgcn_s_setprio(0);
      cur ^= 1;
    } // kt

    // ---- merge the two groups through LDS, normalize, store ----
    __syncthreads();
    if (gq == 1) {
      #pragma unroll
      for (int r = 0; r < 4; ++r) {
        int row = wg * 16 + g * 4 + r;
        if (li == 0) { ML[row * 2] = mrow[r]; ML[row * 2 + 1] = lrow[r]; }
        #pragma unroll
        for (int dt2 = 0; dt2 < 16; ++dt2)
          U[row * 260 + dt2 * 16 + li] = O[dt2][r];
      }
    }
    __syncthreads();
    if (gq == 0) {
      float eA[4], eB[4], invl[4];
      #pragma unroll
      for (int r = 0; r < 4; ++r) {
        int row = wg * 16 + g * 4 + r;
        float mB = ML[row * 2], lB = ML[row * 2 + 1];
        float m = fmaxf(mrow[r], mB);
        eA[r] = __expf(mrow[r] - m);
        eB[r] = __expf(mB - m);
        invl[r] = 1.f / (lrow[r] * eA[r] + lB * eB[r]);
      }
      #pragma unroll
      for (int dt2 = 0; dt2 < 16; ++dt2)
        #pragma unroll
        for (int r = 0; r < 4; ++r) {
          int row = wg * 16 + g * 4 + r;
          float uB = U[row * 260 + dt2 * 16 + li];
          out[((size_t)b * CC + q0 + row) * DD + dt2 * 16 + li] =
              (O[dt2][r] * eA[r] + uB * eB[r]) * invl[r];
        }
    }
    __syncthreads();                            // U region reused by next tile
  } // tt
}

// ---------------------------------------------------------------------------
extern "C" void kernel_launch(void* const* d_in, const int* in_sizes, int n_in,
                              void* d_out, int out_size, void* d_ws, size_t ws_size,
                              hipStream_t stream) {
  const float* x  = (const float*)d_in[0];
  const float* Wq = (const float*)d_in[1];
  const float* bq = (const float*)d_in[2];
  const float* Wk = (const float*)d_in[3];
  const float* bk = (const float*)d_in[4];
  const float* Wv = (const float*)d_in[5];
  const float* bv = (const float*)d_in[6];
  float* out = (float*)d_out;
  (void)in_sizes; (void)n_in; (void)out_size; (void)ws_size;

  // ws layout: cs 2MB | q_rot 16MB | k_rot 16MB | v_t 16MB | wb 384KB
  char* ws = (char*)d_ws;
  float2* cs   = (float2*)ws;
  short* q_rot = (short*)(ws + (2u << 20));
  short* k_rot = q_rot + (size_t)MM * DD;
  short* v_tr  = k_rot + (size_t)MM * DD;
  short* wb    = v_tr + (size_t)MM * DD;

  k_prep <<< 256, 256, 0, stream>>>(Wq, Wk, Wv, wb, cs);
  k_qkv  <<< 512, 256, 0, stream>>>(x, wb, bq, bk, bv, cs, q_rot, k_rot, v_tr);
  k_attn <<< 256, 512, 0, stream>>>(q_rot, k_rot, v_tr, out);
}

// Round 20
// 117.641 us; speedup vs baseline: 1.1827x; 1.1827x over previous
//
#include <hip/hip_runtime.h>
#include <stdint.h>

#define BB 16
#define CC 2048
#define DD 256
#define MM (BB*CC)

typedef __attribute__((ext_vector_type(4))) float f32x4;
typedef __attribute__((ext_vector_type(8))) short bf16x8;
typedef __attribute__((ext_vector_type(4))) short s16x4;

static __device__ __forceinline__ short f2bf(float f) {
  union { float f; uint32_t u; } v; v.f = f;
  uint32_t u = v.u;
  return (short)((u + 0x7FFFu + ((u >> 16) & 1u)) >> 16);
}

// async global->LDS, 16B per lane, dest = uniform base + lane*16
#define GLDS16(gp, lp) __builtin_amdgcn_global_load_lds(                      \
    (const __attribute__((address_space(1))) void*)(gp),                      \
    (__attribute__((address_space(3))) void*)(lp), 16, 0, 0)

// DPP row_ror reduction step over the 16-lane group (ror n)
#define DPP_ROR_F(x, n) __uint_as_float(__builtin_amdgcn_update_dpp(          \
    0, (int)__float_as_uint(x), 0x120 + (n), 0xF, 0xF, false))

// ---------------------------------------------------------------------------
// Kernel 1 (fused prep): blocks 0..63 build the cos/sin table; blocks 64..255
// convert W{q,k,v} f32->bf16 into 24KB half-e steps: step s (kc=s>>1, eh=s&1)
// = [mat 8KB][e_local row 64B, in-row slot XOR (((e>>1)&3)<<4)].
// ---------------------------------------------------------------------------
__global__ __launch_bounds__(256) void k_prep(
    const float* __restrict__ Wq, const float* __restrict__ Wk,
    const float* __restrict__ Wv, short* __restrict__ wb,
    float2* __restrict__ cs) {
  const int bid = blockIdx.x;
  if (bid < 64) {
    int id = bid * 256 + threadIdx.x;            // 16384 threads
    int k = id & 127, pg = id >> 7;
    double th = pow(10000.0, (1.0 - (double)k) * (1.0 / 128.0));
    const double TWO_PI = 6.283185307179586476925287;
    const double INV_2PI = 1.0 / TWO_PI;
    #pragma unroll
    for (int i = 0; i < 16; ++i) {
      int pos = pg * 16 + i;
      double ang = (double)pos * th;
      double red = ang - floor(ang * INV_2PI) * TWO_PI;
      float fr = (float)red;
      cs[(size_t)pos * 128 + k] = make_float2(__cosf(fr), __sinf(fr));
    }
  } else {
    int gid = (bid - 64) * 256 + threadIdx.x;    // 49152 groups of 8B
    int s = gid / 3072;                          // 3072 groups per 24KB step
    int og = gid - s * 3072;
    int mat = og >> 10;                          // 1024 groups per mat slice
    int o = (og & 1023) * 8;                     // byte offset in mat slice
    int e_local = o >> 6;
    int e = (s & 1) * 128 + e_local;
    int kc = s >> 1;
    int c4 = ((o & 63) ^ (((e >> 1) & 3) << 4)) >> 3;
    const float* W = (mat == 0) ? Wq : (mat == 1) ? Wk : Wv;
    f32x4 wv = *(const f32x4*)(W + (size_t)e * DD + kc * 32 + c4 * 4);
    s16x4 b4;
    b4[0] = f2bf(wv[0]); b4[1] = f2bf(wv[1]); b4[2] = f2bf(wv[2]); b4[3] = f2bf(wv[3]);
    *(s16x4*)((char*)wb + (size_t)gid * 8) = b4;
  }
}

// ---------------------------------------------------------------------------
// Kernel 2: fused QKV projection + RoPE. Proven resources (256 thr, 64 rows,
// 80KB LDS -> 2 blocks/CU) + single-barrier slot: W staged in 24KB half-e
// steps, double-buffered: slot = { vmcnt(0); barrier; STAGE(next); compute }.
// ---------------------------------------------------------------------------
__global__ __launch_bounds__(256, 2) void k_qkv(
    const float* __restrict__ x, const short* __restrict__ wb,
    const float* __restrict__ bq, const float* __restrict__ bk,
    const float* __restrict__ bv, const float2* __restrict__ cs,
    short* __restrict__ q_rot, short* __restrict__ k_rot,
    short* __restrict__ v_t)
{
  __shared__ char SM[81920];           // xs 32KB | wsh dbuf 2x24KB
  short* xs = (short*)SM;              // [64 rows][512B], swz (row&7)<<4
  char* wsh = SM + 32768;
  const int t = threadIdx.x;
  const int lane = t & 63, w = t >> 6; // 4 waves
  const int g = lane >> 4, li = lane & 15;
  const int m0 = blockIdx.x * 64;

  // stage x tile (f32 -> bf16), swizzled rows 512B
  #pragma unroll
  for (int i = 0; i < 16; ++i) {
    int chunk = i * 256 + t;           // 4096 chunks of 4 f32
    int row = chunk >> 6, c4 = chunk & 63;
    f32x4 xv = *(const f32x4*)(x + (size_t)(m0 + row) * DD + c4 * 4);
    s16x4 b4;
    b4[0] = f2bf(xv[0]); b4[1] = f2bf(xv[1]); b4[2] = f2bf(xv[2]); b4[3] = f2bf(xv[3]);
    *(s16x4*)((char*)xs + row * 512 + ((c4 * 8) ^ ((row & 7) << 4))) = b4;
  }

  auto STAGE = [&](int buf, int s) {   // 24 x 1KB chunks over 4 waves
    #pragma unroll
    for (int i = 0; i < 6; ++i) {
      int cc = i * 4 + w;
      const char* src = (const char*)wb + s * 24576 + cc * 1024 + lane * 16;
      GLDS16(src, wsh + buf * 24576 + cc * 1024);
    }
  };

  STAGE(0, 0);
  __syncthreads();                     // xs ready; STAGE(0) issued

  f32x4 zero4 = {0.f, 0.f, 0.f, 0.f};
  f32x4 accQ[16], accK[16], accV[16];
  #pragma unroll
  for (int nt = 0; nt < 16; ++nt) { accQ[nt] = zero4; accK[nt] = zero4; accV[nt] = zero4; }

  #pragma unroll
  for (int kc = 0; kc < 8; ++kc) {
    #pragma unroll
    for (int eh = 0; eh < 2; ++eh) {
      const int s = kc * 2 + eh;
      asm volatile("s_waitcnt vmcnt(0)" ::: "memory");  // my STAGE(s) landed
      __builtin_amdgcn_sched_barrier(0);
      __builtin_amdgcn_s_barrier();    // all stages landed + all done s-1
      if (s + 1 < 16) STAGE((s + 1) & 1, s + 1);        // WAR-safe after bar

      const int arow = w * 16 + li;
      bf16x8 a = *(const bf16x8*)((char*)xs + arow * 512 +
                                  (((kc * 64) + g * 16) ^ ((arow & 7) << 4)));
      const char* Wb = wsh + (s & 1) * 24576;
      #pragma unroll
      for (int ntl = 0; ntl < 8; ++ntl) {
        const int nt = eh * 8 + ntl;
        int e_local = ntl * 16 + li;
        int off = e_local * 64 + ((g * 16) ^ (((e_local >> 1) & 3) << 4));
        bf16x8 fq = *(const bf16x8*)(Wb + off);
        bf16x8 fk = *(const bf16x8*)(Wb + 8192 + off);
        bf16x8 fv = *(const bf16x8*)(Wb + 16384 + off);
        accQ[nt] = __builtin_amdgcn_mfma_f32_16x16x32_bf16(a, fq, accQ[nt], 0, 0, 0);
        accK[nt] = __builtin_amdgcn_mfma_f32_16x16x32_bf16(a, fk, accK[nt], 0, 0, 0);
        accV[nt] = __builtin_amdgcn_mfma_f32_16x16x32_bf16(a, fv, accV[nt], 0, 0, 0);
      }
    }
  }

  // q,k epilogue: bias + RoPE -> LDS row tiles (pitch 528) -> b128 stores
  __syncthreads();
  {
    char* Tq = SM;            // [64 rows][264 shorts] = 33792 B
    char* Tk = SM + 33792;    // same
    #pragma unroll
    for (int nt = 0; nt < 16; ++nt) {
      int e = nt * 16 + li;
      float bQ = bq[e], bK = bk[e];
      #pragma unroll
      for (int r = 0; r < 4; ++r) {
        int cloc = w * 16 + g * 4 + r;
        int m = m0 + cloc;
        float2 csv = cs[(size_t)(m & (CC - 1)) * 128 + (e >> 1)];
        float vq = accQ[nt][r] + bQ;
        float oq = __shfl_xor(vq, 1);
        vq = csv.x * vq + ((e & 1) ? csv.y * oq : -csv.y * oq);
        *(short*)(Tq + cloc * 528 + e * 2) = f2bf(vq * 0.0625f);
        float vk = accK[nt][r] + bK;
        float ok = __shfl_xor(vk, 1);
        vk = csv.x * vk + ((e & 1) ? csv.y * ok : -csv.y * ok);
        *(short*)(Tk + cloc * 528 + e * 2) = f2bf(vk);
      }
    }
    __syncthreads();
    #pragma unroll
    for (int it = 0; it < 8; ++it) {
      int chunk = it * 256 + t;                 // 2048 chunks of 16B
      int c = chunk >> 5, e32 = chunk & 31;
      int4 vq4 = *(const int4*)(Tq + c * 528 + e32 * 16);
      int4 vk4 = *(const int4*)(Tk + c * 528 + e32 * 16);
      *(int4*)(q_rot + (size_t)(m0 + c) * DD + e32 * 8) = vq4;
      *(int4*)(k_rot + (size_t)(m0 + c) * DD + e32 * 8) = vk4;
    }
  }
  // v epilogue: LDS transpose -> coalesced stores
  __syncthreads();
  #pragma unroll
  for (int nt = 0; nt < 16; ++nt) {
    int e = nt * 16 + li;
    float bias = bv[e];
    #pragma unroll
    for (int r = 0; r < 4; ++r) {
      int cloc = w * 16 + g * 4 + r;
      *(short*)(SM + e * 144 + cloc * 2) = f2bf(accV[nt][r] + bias);
    }
  }
  __syncthreads();
  {
    const int bb = m0 >> 11, c0 = m0 & (CC - 1);
    #pragma unroll
    for (int it = 0; it < 8; ++it) {
      int chunk = it * 256 + t;
      int e = chunk >> 3, c8 = chunk & 7;
      int4 vv = *(const int4*)(SM + e * 144 + c8 * 16);
      *(int4*)(v_t + ((size_t)(bb * DD + e)) * CC + c0 + c8 * 8) = vv;
    }
  }
}

// ---------------------------------------------------------------------------
// Kernel 3: causal flash attention (proven round-14 version).
// 256 blocks x 512 thr = 1 block/CU, 8 waves (2/SIMD). Pair {j, 31-j} ->
// exactly 33 group-iters. 2 kv-groups of 4 waves, per-group dbuf K+V.
// Single barrier/slot. DPP softmax; LDS merge.
// ---------------------------------------------------------------------------
__global__ __launch_bounds__(512, 2) void k_attn(
    const short* __restrict__ q_rot, const short* __restrict__ k_rot,
    const short* __restrict__ v_t, float* __restrict__ out)
{
  // LDS: KV [0,128K): group g buf b at (g*2+b)*32768 {K 16KB | V 16KB}
  //      U  [64K, 64K+66560)  (merge, reuses group-1 KV space + a bit)
  //      P  [132608, +8*1280) ; ML [142848, +512)
  __shared__ char SM[143360];
  const int t = threadIdx.x;
  const int lane = t & 63, w = t >> 6;          // 8 waves
  const int wg = w & 3, gq = w >> 2;            // wave-in-group, kv-group
  const int g = lane >> 4, li = lane & 15;

  const int p = blockIdx.x;                     // 256 blocks, 1/CU
  const int b = p & 15;                         // batch -> XCD p%8 fixed
  const int j = p >> 4;                         // 0..15 pair index

  const short* kbase = k_rot + (size_t)b * CC * DD;
  const short* vbase = v_t  + (size_t)b * DD * CC;

  float* U  = (float*)(SM + 65536);             // [64][260] f32
  float* ML = (float*)(SM + 142848);            // [64][2]
  char* Pb = SM + 132608 + w * 1280;            // [16 q][40 sh] pitch 80B

  f32x4 zero4 = {0.f, 0.f, 0.f, 0.f};

  for (int tt = 0; tt < 2; ++tt) {
    const int qt = tt ? (31 - j) : j;           // pair sums to 33 group-iters
    const int q0 = qt * 64;
    const int NTg = qt + 1;                     // kv tiles of 32 per group
    const int kvoff = gq * 32 * NTg;            // group kv start

    // Q fragments: rows q0 + wg*16 + li
    const short* qb = q_rot + ((size_t)b * CC + q0 + wg * 16 + li) * DD;
    bf16x8 qf[8];
    #pragma unroll
    for (int dc = 0; dc < 8; ++dc)
      qf[dc] = *(const bf16x8*)(qb + dc * 32 + g * 8);

    f32x4 O[16];
    #pragma unroll
    for (int i = 0; i < 16; ++i) O[i] = zero4;
    float mrow[4], lrow[4];
    #pragma unroll
    for (int r = 0; r < 4; ++r) { mrow[r] = -__builtin_inff(); lrow[r] = 0.f; }

    auto STAGE = [&](int buf, int kt) {         // 8 GLDS16 per wave
      const int k0s = kvoff + kt * 32;
      char* dst = SM + (size_t)(gq * 2 + buf) * 32768;
      #pragma unroll
      for (int i = 0; i < 4; ++i) {             // K tile: 16 x 1KB chunks
        int c = i * 4 + wg;
        int row = 2 * c + (lane >> 5);
        int cb = ((lane & 31) * 16) ^ ((row & 7) << 4);
        const char* src = (const char*)(kbase + (size_t)(k0s + row) * DD) + cb;
        GLDS16(src, dst + c * 1024);
      }
      #pragma unroll
      for (int i = 0; i < 4; ++i) {             // V tile: 16 x 1KB chunks
        int c = i * 4 + wg;
        int d = 16 * c + (lane >> 2);
        int sb = (((lane & 3) ^ ((lane >> 3) & 3)) * 16);
        const char* src = (const char*)(vbase + (size_t)d * CC + k0s) + sb;
        GLDS16(src, dst + 16384 + c * 1024);
      }
    };

    int cur = 0;
    STAGE(0, 0);
    for (int kt = 0; kt < NTg; ++kt) {
      const int k0 = kvoff + kt * 32;
      asm volatile("s_waitcnt vmcnt(0)" ::: "memory");   // my stage landed
      __builtin_amdgcn_sched_barrier(0);
      __builtin_amdgcn_s_barrier();             // all stages landed AND all
                                                // waves done reading kt-1
      if (kt + 1 < NTg) STAGE(cur ^ 1, kt + 1); // WAR-safe after barrier

      const char* Kb = SM + (size_t)(gq * 2 + cur) * 32768;
      const char* Vb = Kb + 16384;

      // S = Q K^T (scale folded into q)
      f32x4 S[2];
      S[0] = zero4; S[1] = zero4;
      __builtin_amdgcn_s_setprio(1);
      #pragma unroll
      for (int dc = 0; dc < 8; ++dc) {
        #pragma unroll
        for (int nt = 0; nt < 2; ++nt) {
          int krow = nt * 16 + li;
          bf16x8 kf = *(const bf16x8*)(Kb + krow * 512 +
                                       (((dc * 64) + g * 16) ^ ((krow & 7) << 4)));
          S[nt] = __builtin_amdgcn_mfma_f32_16x16x32_bf16(qf[dc], kf, S[nt], 0, 0, 0);
        }
      }
      __builtin_amdgcn_s_setprio(0);

      // causal mask (finite sentinel); uniform cheap test
      if (k0 + 31 > q0) {
        #pragma unroll
        for (int nt = 0; nt < 2; ++nt)
          #pragma unroll
          for (int r = 0; r < 4; ++r)
            if ((k0 + nt * 16 + li) > (q0 + wg * 16 + g * 4 + r))
              S[nt][r] = -1.0e30f;
      }

      // online softmax, DPP row_ror reductions, defer-max (THR=8)
      float mxr[4];
      #pragma unroll
      for (int r = 0; r < 4; ++r) {
        float mx = fmaxf(S[0][r], S[1][r]);
        mx = fmaxf(mx, DPP_ROR_F(mx, 8));
        mx = fmaxf(mx, DPP_ROR_F(mx, 4));
        mx = fmaxf(mx, DPP_ROR_F(mx, 2));
        mx = fmaxf(mx, DPP_ROR_F(mx, 1));
        mxr[r] = mx;
      }
      int need = 0;
      #pragma unroll
      for (int r = 0; r < 4; ++r) need |= (mxr[r] > mrow[r] + 8.f) ? 1 : 0;
      if (__any(need)) {
        #pragma unroll
        for (int r = 0; r < 4; ++r) {
          float mnew = fmaxf(mrow[r], mxr[r]);
          float al = __expf(mrow[r] - mnew);
          mrow[r] = mnew;
          lrow[r] *= al;
          #pragma unroll
          for (int dt2 = 0; dt2 < 16; ++dt2) O[dt2][r] *= al;
        }
      }
      #pragma unroll
      for (int r = 0; r < 4; ++r) {
        float rsum = 0.f;
        #pragma unroll
        for (int nt = 0; nt < 2; ++nt) {
          float pv = __expf(S[nt][r] - mrow[r]);
          S[nt][r] = pv;
          rsum += pv;
        }
        rsum += DPP_ROR_F(rsum, 8);
        rsum += DPP_ROR_F(rsum, 4);
        rsum += DPP_ROR_F(rsum, 2);
        rsum += DPP_ROR_F(rsum, 1);
        lrow[r] += rsum;
      }

      // P (C-layout) -> per-wave LDS (pitch 80) -> A-frag
      #pragma unroll
      for (int nt = 0; nt < 2; ++nt)
        #pragma unroll
        for (int r = 0; r < 4; ++r)
          *(short*)(Pb + (g * 4 + r) * 80 + (nt * 16 + li) * 2) = f2bf(S[nt][r]);

      bf16x8 pf = *(const bf16x8*)(Pb + li * 80 + g * 16);

      // O += P V
      __builtin_amdgcn_s_setprio(1);
      #pragma unroll
      for (int dt2 = 0; dt2 < 16; ++dt2) {
        bf16x8 vf = *(const bf16x8*)(Vb + (dt2 * 16 + li) * 64 +
                                     ((g * 16) ^ (((li >> 1) & 3) << 4)));
        O[dt2] = __builtin_amdgcn_mfma_f32_16x16x32_bf16(pf, vf, O[dt2], 0, 0, 0);
      }
      __builtin_amdgcn_s_setprio(0);
      cur ^= 1;
    } // kt

    // ---- merge the two groups through LDS, normalize, store ----
    __syncthreads();
    if (gq == 1) {
      #pragma unroll
      for (int r = 0; r < 4; ++r) {
        int row = wg * 16 + g * 4 + r;
        if (li == 0) { ML[row * 2] = mrow[r]; ML[row * 2 + 1] = lrow[r]; }
        #pragma unroll
        for (int dt2 = 0; dt2 < 16; ++dt2)
          U[row * 260 + dt2 * 16 + li] = O[dt2][r];
      }
    }
    __syncthreads();
    if (gq == 0) {
      float eA[4], eB[4], invl[4];
      #pragma unroll
      for (int r = 0; r < 4; ++r) {
        int row = wg * 16 + g * 4 + r;
        float mB = ML[row * 2], lB = ML[row * 2 + 1];
        float m = fmaxf(mrow[r], mB);
        eA[r] = __expf(mrow[r] - m);
        eB[r] = __expf(mB - m);
        invl[r] = 1.f / (lrow[r] * eA[r] + lB * eB[r]);
      }
      #pragma unroll
      for (int dt2 = 0; dt2 < 16; ++dt2)
        #pragma unroll
        for (int r = 0; r < 4; ++r) {
          int row = wg * 16 + g * 4 + r;
          float uB = U[row * 260 + dt2 * 16 + li];
          out[((size_t)b * CC + q0 + row) * DD + dt2 * 16 + li] =
              (O[dt2][r] * eA[r] + uB * eB[r]) * invl[r];
        }
    }
    __syncthreads();                            // U region reused by next tile
  } // tt
}

// ---------------------------------------------------------------------------
extern "C" void kernel_launch(void* const* d_in, const int* in_sizes, int n_in,
                              void* d_out, int out_size, void* d_ws, size_t ws_size,
                              hipStream_t stream) {
  const float* x  = (const float*)d_in[0];
  const float* Wq = (const float*)d_in[1];
  const float* bq = (const float*)d_in[2];
  const float* Wk = (const float*)d_in[3];
  const float* bk = (const float*)d_in[4];
  const float* Wv = (const float*)d_in[5];
  const float* bv = (const float*)d_in[6];
  float* out = (float*)d_out;
  (void)in_sizes; (void)n_in; (void)out_size; (void)ws_size;

  // ws layout: cs 2MB | q_rot 16MB | k_rot 16MB | v_t 16MB | wb 384KB
  char* ws = (char*)d_ws;
  float2* cs   = (float2*)ws;
  short* q_rot = (short*)(ws + (2u << 20));
  short* k_rot = q_rot + (size_t)MM * DD;
  short* v_tr  = k_rot + (size_t)MM * DD;
  short* wb    = v_tr + (size_t)MM * DD;

  k_prep <<< 256, 256, 0, stream>>>(Wq, Wk, Wv, wb, cs);
  k_qkv  <<< 512, 256, 0, stream>>>(x, wb, bq, bk, bv, cs, q_rot, k_rot, v_tr);
  k_attn <<< 256, 512, 0, stream>>>(q_rot, k_rot, v_tr, out);
}